// Round 15
// baseline (503.261 us; speedup 1.0000x reference)
//
#include <hip/hip_runtime.h>
#include <hip/hip_cooperative_groups.h>
#include <math.h>

namespace cg = cooperative_groups;

#define B     64
#define NCAP  64
#define LV    197
#define LT    32
#define C     512
#define NSP   196
#define NKEEP 98
#define HID   102
#define KEEPED 49

// Workspace layout (float element offsets). Total ~80 MB (< proven 106.8 MB).
#define OFF_ATTNX   12608                     // B*NSP
#define OFF_WSMAT   25152                     // u16 B*NSP*KEEPED (holds bf16 exp(Ws))
#define OFF_WT      639808                    // u16 2*512*512 (bf16 wi2t^T / wt2i^T)
#define OFF_GLOT    1688384                   // C*NCAP  (packed float4: [c/4][i][4])
#define OFF_ATTNYT  1721152                   // 4096*196 floats (transposed [b][i][s])
#define OFF_IMGT    14164800                  // u16 64*7*32*512 fragment-major imgT
#define OFF_QBB     17834816                  // u16 64*6*16*512 fragment-major Qbb
#define OFF_QCAP    19407680                  // u16 64*32*512 row-major cap rows (qproj input)
#define OFF_W1TF    19931968                  // u16 7*16*512 fragment-major w1^T (N=112 pad, K=512)
#define OFF_W2TF    19960640                  // u16 4*4*512 fragment-major w2^T (N=64 pad, K=128 pad)

typedef unsigned int u32;
typedef unsigned short u16;
typedef __bf16 bf16x8 __attribute__((ext_vector_type(8)));
typedef float f32x4 __attribute__((ext_vector_type(4)));
typedef unsigned int uint4v __attribute__((ext_vector_type(4)));

__device__ __forceinline__ u16 f2bf(float f) {
    u32 u = __builtin_bit_cast(u32, f);
    return (u16)((u + 0x7FFFu + ((u >> 16) & 1u)) >> 16);
}
__device__ __forceinline__ bf16x8 ld_bf8(const u16* p) {
    uint4v v = *reinterpret_cast<const uint4v*>(p);
    return __builtin_bit_cast(bf16x8, v);
}

__device__ __forceinline__ float gelu_exact(float x) {
    return 0.5f * x * (1.f + erff(x * 0.70710678118654752f));
}

// ================================================================ section bodies (shared by
// fused kernel and fallback kernels; all bit-identical to round-12 measured code)

__device__ __forceinline__ void sec_capnorm(int e, int t,
                                            const float* __restrict__ cap,
                                            float* __restrict__ gloT,
                                            u16* __restrict__ Qbbf,
                                            u16* __restrict__ Qcap) {
    // 256-thread body (guarded by caller); no barriers inside
    int i = e >> 3, tg = e & 7;
    int lane = t & 63, wv = t >> 6;
    int tt = tg * 4 + wv;
    const float* row = cap + ((size_t)i * LT + tt) * C;
    float v[8]; float ss = 0.f;
#pragma unroll
    for (int q = 0; q < 8; ++q) { v[q] = row[lane + 64 * q]; ss += v[q] * v[q]; }
    for (int o = 32; o > 0; o >>= 1) ss += __shfl_down(ss, o);
    ss = __shfl(ss, 0);
    float inv = 1.f / fmaxf(sqrtf(ss), 1e-12f);
    u16* qrow = Qcap + ((size_t)i * 32 + tt) * C;
    int mi = tt >> 4, l15f = tt & 15;
    u16* qfb = Qbbf + (size_t)(i * 6 + mi) * 16 * 512;
#pragma unroll
    for (int q = 0; q < 8; ++q) {
        float n = v[q] * inv;
        u16 nb = f2bf(n);
        int c = lane + 64 * q;
        qrow[c] = nb;
        int ks = c >> 5, quadf = (c >> 3) & 3, jf = c & 7;
        qfb[(size_t)ks * 512 + (quadf * 16 + l15f) * 8 + jf] = nb;
        if (tt == 0) gloT[(c >> 2) * (NCAP * 4) + i * 4 + (c & 3)] = n;
    }
}

template <int NT>
__device__ __forceinline__ void sec_wt(int e, int t, u16* shb,
                                       const float* __restrict__ wi2t,
                                       const float* __restrict__ wt2i,
                                       u16* __restrict__ wT) {
    // all NT threads participate (internal barrier)
    int mat = e >> 6, ty = e & 63, jg = ty >> 3, cg = ty & 7;
    const float* W = mat ? wt2i : wi2t;
    u16 (*tile)[65] = (u16(*)[65])shb;
    for (int f = t; f < 4096; f += NT) {
        int cc2 = f >> 6, jj = f & 63;
        tile[jj][cc2] = f2bf(W[(size_t)(cg * 64 + cc2) * 512 + jg * 64 + jj]);
    }
    __syncthreads();
    for (int f = t; f < 4096; f += NT) {
        int jj = f >> 6, cc2 = f & 63;
        wT[((size_t)mat * 512 + jg * 64 + jj) * 512 + cg * 64 + cc2] = tile[jj][cc2];
    }
}

template <int NT>
__device__ __forceinline__ void sec_w1t(int nt, int t,
                                        const float* __restrict__ w1,
                                        u16* __restrict__ w1Tf) {
    u32* outp = (u32*)w1Tf + (size_t)nt * 16 * 256;
    for (int f = t; f < 16 * 256; f += NT) {
        int ks = f >> 8, g = f & 255;
        int lane_o = g >> 2, j2 = g & 3;
        int l15o = lane_o & 15, quado = lane_o >> 4;
        int kk = ks * 32 + quado * 8 + 2 * j2;
        int n = nt * 16 + l15o;
        u32 lo = 0, hi = 0;
        if (n < HID) {
            lo = f2bf(w1[(size_t)kk * HID + n]);
            hi = f2bf(w1[(size_t)(kk + 1) * HID + n]);
        }
        outp[ks * 256 + g] = lo | (hi << 16);
    }
}

template <int NT>
__device__ __forceinline__ void sec_w2t(int t,
                                        const float* __restrict__ w2,
                                        u16* __restrict__ w2Tf) {
    u32* outp = (u32*)w2Tf;
    for (int f = t; f < 16 * 256; f += NT) {
        int tile = f >> 8, g = f & 255;
        int nt2 = tile >> 2, ks2 = tile & 3;
        int lane_o = g >> 2, j2 = g & 3;
        int l15o = lane_o & 15, quado = lane_o >> 4;
        int kk0 = ks2 * 32 + quado * 8 + 2 * j2;
        int n = nt2 * 16 + l15o;
        u32 lo = 0, hi = 0;
        if (n < KEEPED) {
            if (kk0 < HID)     lo = f2bf(w2[(size_t)kk0 * KEEPED + n]);
            if (kk0 + 1 < HID) hi = f2bf(w2[(size_t)(kk0 + 1) * KEEPED + n]);
        }
        outp[tile * 256 + g] = lo | (hi << 16);
    }
}

__device__ __forceinline__ void sec_qproj(int idx, int t,
                                          const u16* __restrict__ wT,
                                          const float* __restrict__ bi2t,
                                          const float* __restrict__ bt2i,
                                          const u16* __restrict__ Qcap,
                                          u16* __restrict__ Qbbf) {
    int i = idx & 63, p = idx >> 6;
    int lane = t & 63, wu = t >> 6;
    int l15 = lane & 15, quad = lane >> 4;
    int mat = wu >> 2;
    int miq = (wu >> 1) & 1;
    int nh  = wu & 1;
    int ni0 = p * 8 + nh * 4;
    const u16* Arow = Qcap + ((size_t)i * 32 + miq * 16 + l15) * 512;
    const u16* Wm   = wT + (size_t)mat * 512 * 512;
    f32x4 acc[4];
#pragma unroll
    for (int n = 0; n < 4; ++n) acc[n] = (f32x4){0.f, 0.f, 0.f, 0.f};
    bf16x8 A = ld_bf8(Arow + quad * 8);
    bf16x8 Bf[4];
#pragma unroll
    for (int n = 0; n < 4; ++n)
        Bf[n] = ld_bf8(Wm + (size_t)((ni0 + n) * 16 + l15) * 512 + quad * 8);
    for (int ks = 0; ks < 16; ++ks) {
        bf16x8 An; bf16x8 Bn[4];
        if (ks < 15) {
            An = ld_bf8(Arow + (ks + 1) * 32 + quad * 8);
#pragma unroll
            for (int n = 0; n < 4; ++n)
                Bn[n] = ld_bf8(Wm + (size_t)((ni0 + n) * 16 + l15) * 512 + (ks + 1) * 32 + quad * 8);
        }
#pragma unroll
        for (int n = 0; n < 4; ++n)
            acc[n] = __builtin_amdgcn_mfma_f32_16x16x32_bf16(A, Bf[n], acc[n], 0, 0, 0);
        A = An;
#pragma unroll
        for (int n = 0; n < 4; ++n) Bf[n] = Bn[n];
    }
    const float* bias = mat ? bt2i : bi2t;
#pragma unroll
    for (int n = 0; n < 4; ++n) {
        int j = (ni0 + n) * 16 + l15;
        float bj = bias[j];
        int ksf = j >> 5, quadf = (j >> 3) & 3, jf = j & 7;
#pragma unroll
        for (int r = 0; r < 4; ++r) {
            int q = 32 + mat * 32 + miq * 16 + quad * 4 + r;
            int mi = q >> 4, l15f = q & 15;
            Qbbf[(size_t)((i * 6 + mi) * 16 + ksf) * 512 + (quadf * 16 + l15f) * 8 + jf]
                = f2bf(acc[n][r] + bj);
        }
    }
}

__device__ __forceinline__ void sec_imgrow(int e, int t, u16* shu,
                                           const float* __restrict__ img,
                                           const u16* __restrict__ w1Tf,
                                           const u16* __restrict__ w2Tf,
                                           const float* __restrict__ gamw,
                                           const float* __restrict__ betw,
                                           const float* __restrict__ b1,
                                           const float* __restrict__ b2,
                                           const float* __restrict__ scale_p,
                                           float* __restrict__ attn_x,
                                           u16* __restrict__ WsM16) {
    int b = e / 13, sg = e - b * 13;
    int s0 = sg * 16;
    u16* LNb = shu;              // [16][520]
    u16* Hb  = shu + 16 * 520;   // [16][136]
    int lane = t & 63, wu = t >> 6;
    int l15 = lane & 15, quad = lane >> 4;

    {
        int rr0 = 2 * wu, rr1 = 2 * wu + 1;
        int sA = s0 + rr0, sB = s0 + rr1;
        int sAc = sA < NSP ? sA : NSP - 1;
        int sBc = sB < NSP ? sB : NSP - 1;
        const float* rowA = img + ((size_t)b * LV + 1 + sAc) * C;
        const float* rowB = img + ((size_t)b * LV + 1 + sBc) * C;
        const float* cls  = img + (size_t)b * LV * C;
        float v0[8], v1[8];
        float sm0 = 0, ss0 = 0, dd0 = 0, sm1 = 0, ss1 = 0, dd1 = 0, sc = 0;
#pragma unroll
        for (int q = 0; q < 8; ++q) {
            int c = lane + 64 * q;
            float cv = cls[c];
            v0[q] = rowA[c]; v1[q] = rowB[c];
            sm0 += v0[q]; ss0 += v0[q] * v0[q]; dd0 += v0[q] * cv;
            sm1 += v1[q]; ss1 += v1[q] * v1[q]; dd1 += v1[q] * cv;
            sc  += cv * cv;
        }
        for (int o = 32; o > 0; o >>= 1) {
            sm0 += __shfl_down(sm0, o); ss0 += __shfl_down(ss0, o); dd0 += __shfl_down(dd0, o);
            sm1 += __shfl_down(sm1, o); ss1 += __shfl_down(ss1, o); dd1 += __shfl_down(dd1, o);
            sc  += __shfl_down(sc, o);
        }
        sm0 = __shfl(sm0, 0); ss0 = __shfl(ss0, 0);
        sm1 = __shfl(sm1, 0); ss1 = __shfl(ss1, 0);
        float mean0 = sm0 * (1.f / C);
        float rstd0 = 1.f / sqrtf(ss0 * (1.f / C) - mean0 * mean0 + 1e-5f);
        float mean1 = sm1 * (1.f / C);
        float rstd1 = 1.f / sqrtf(ss1 * (1.f / C) - mean1 * mean1 + 1e-5f);
        if (lane == 0) {
            float inv0 = 1.f / fmaxf(sqrtf(sc), 1e-12f);
            if (sA < NSP) attn_x[b * NSP + sA] = dd0 * inv0 * (1.f / fmaxf(sqrtf(ss0), 1e-12f));
            if (sB < NSP) attn_x[b * NSP + sB] = dd1 * inv0 * (1.f / fmaxf(sqrtf(ss1), 1e-12f));
        }
#pragma unroll
        for (int q = 0; q < 8; ++q) {
            int c = lane + 64 * q;
            float g = gamw[c], be = betw[c];
            LNb[rr0 * 520 + c] = f2bf((v0[q] - mean0) * rstd0 * g + be);
            LNb[rr1 * 520 + c] = f2bf((v1[q] - mean1) * rstd1 * g + be);
        }
    }
    __syncthreads();
    if (wu < 7) {
        const u16* W1b = w1Tf + (size_t)wu * 16 * 512;
        f32x4 h4 = (f32x4){0.f, 0.f, 0.f, 0.f};
        for (int ks = 0; ks < 16; ++ks) {
            bf16x8 A = ld_bf8(LNb + l15 * 520 + ks * 32 + quad * 8);
            bf16x8 Bv = ld_bf8(W1b + ks * 512 + lane * 8);
            h4 = __builtin_amdgcn_mfma_f32_16x16x32_bf16(A, Bv, h4, 0, 0, 0);
        }
        int col = wu * 16 + l15;
        if (col < HID) {
            float bb = b1[col];
#pragma unroll
            for (int r = 0; r < 4; ++r)
                Hb[(quad * 4 + r) * 136 + col] = f2bf(gelu_exact(h4[r] + bb));
        } else {
#pragma unroll
            for (int r = 0; r < 4; ++r) Hb[(quad * 4 + r) * 136 + col] = 0;
        }
    } else {
        for (int f = lane; f < 16 * 24; f += 64) {
            int row = f / 24, cc = 112 + f % 24;
            Hb[row * 136 + cc] = 0;
        }
    }
    __syncthreads();
    if (wu < 4) {
        const u16* W2b = w2Tf + (size_t)wu * 4 * 512;
        f32x4 a2 = (f32x4){0.f, 0.f, 0.f, 0.f};
        for (int ks2 = 0; ks2 < 4; ++ks2) {
            bf16x8 A2 = ld_bf8(Hb + l15 * 136 + ks2 * 32 + quad * 8);
            bf16x8 B2 = ld_bf8(W2b + ks2 * 512 + lane * 8);
            a2 = __builtin_amdgcn_mfma_f32_16x16x32_bf16(A2, B2, a2, 0, 0, 0);
        }
        int k = wu * 16 + l15;
        if (k < KEEPED) {
            float scale = scale_p[0], bk = b2[k];
#pragma unroll
            for (int r = 0; r < 4; ++r) {
                int row = quad * 4 + r;
                if (s0 + row < NSP)
                    WsM16[((size_t)b * NSP + s0 + row) * 49 + k] = f2bf(expf((a2[r] + bk) * scale));
            }
        }
    }
}

__device__ __forceinline__ void sec_attny(int e, int t, u16* shu,
                                          const float* __restrict__ img,
                                          const float* __restrict__ gloT,
                                          float* __restrict__ attn_yT) {
    int b = e / 25;
    int s0 = (e - b * 25) * 8;
    int R = NSP - s0; if (R > 8) R = 8;
    float (*xr)[C] = (float(*)[C])shu;     // 16 KB overlay
    float* rnorm = (float*)shu + 4096;

    for (int f = t; f < R * C; f += 512) {
        int rr = f >> 9, c = f & 511;
        xr[rr][c] = img[((size_t)b * LV + 1 + s0 + rr) * C + c];
    }
    __syncthreads();
    {
        int row = t >> 6, l = t & 63;
        if (row < R) {
            float ss = 0.f;
            for (int c = l; c < C; c += 64) { float v = xr[row][c]; ss += v * v; }
            for (int o = 32; o > 0; o >>= 1) ss += __shfl_down(ss, o);
            if (l == 0) rnorm[row] = 1.f / fmaxf(sqrtf(ss), 1e-12f);
        }
    }
    __syncthreads();
    for (int f = t; f < R * C; f += 512) {
        int rr = f >> 9, c = f & 511;
        xr[rr][c] *= rnorm[rr];
    }
    __syncthreads();
    int i = t & 63, w = t >> 6;
    if (w < R) {
        float a0 = 0.f;
        const float4* g4 = (const float4*)gloT;   // packed [c4][i][4]
        const float4* x4 = (const float4*)xr[w];
        for (int c4 = 0; c4 < C / 4; ++c4) {
            float4 g = g4[c4 * NCAP + i];
            float4 x0 = x4[c4];
            a0 += x0.x * g.x + x0.y * g.y + x0.z * g.z + x0.w * g.w;
        }
        attn_yT[((size_t)b * NCAP + i) * NSP + s0 + w] = a0;
    }
}

__device__ __forceinline__ void sec_imgt(int e, int t, u16* shu,
                                         const float* __restrict__ img,
                                         u16* __restrict__ imgTf) {
    int b = e >> 3, cg = e & 7;
    for (int f = t; f < 64 * 27; f += 512) shu[(f / 27) * 224 + 197 + (f % 27)] = 0;
    int cc = t & 63;
    for (int sb = t >> 6; sb < 197; sb += 8) {
        float v = img[((size_t)b * LV + sb) * C + cg * 64 + cc];
        shu[cc * 224 + sb] = f2bf(v);
    }
    __syncthreads();
    const u32* Tu = (const u32*)shu;
    u32* outp = (u32*)imgTf + (size_t)b * 7 * 32 * 256;
    for (int f = t; f < 7 * 4 * 256; f += 512) {
        int ks = f >> 10, rem = f & 1023;
        int ctl = rem >> 8, g = rem & 255;
        int lane_o = g >> 2, j2 = g & 3;
        int quad_o = lane_o >> 4, l15_o = lane_o & 15;
        int ccl = ctl * 16 + l15_o;
        int s = ks * 32 + quad_o * 8 + 2 * j2;
        u32 v = Tu[ccl * 112 + (s >> 1)];
        outp[(size_t)(ks * 32 + cg * 4 + ctl) * 256 + g] = v;
    }
}

// ---------------------------------------------------------------- k_fused (512 blocks, 512 thr, cooperative):
// phase A = k_pre tasks (0..647) | grid.sync | phase B = k_mid tasks (0..3199).
// Replaces the k_pre->k_mid launch boundary (~35 us per r7<->r11 ledger) with one grid barrier.
__global__ __launch_bounds__(512, 4) void k_fused(const float* __restrict__ img,
                                                  const float* __restrict__ cap,
                                                  const float* __restrict__ wi2t,
                                                  const float* __restrict__ wt2i,
                                                  const float* __restrict__ w1,
                                                  const float* __restrict__ w2,
                                                  const float* __restrict__ bi2t,
                                                  const float* __restrict__ bt2i,
                                                  const float* __restrict__ gamw,
                                                  const float* __restrict__ betw,
                                                  const float* __restrict__ b1,
                                                  const float* __restrict__ b2,
                                                  const float* __restrict__ scale_p,
                                                  float* __restrict__ gloT,
                                                  u16* __restrict__ Qbbf,
                                                  u16* __restrict__ Qcap,
                                                  u16* __restrict__ wT,
                                                  u16* __restrict__ w1Tf,
                                                  u16* __restrict__ w2Tf,
                                                  float* __restrict__ attn_x,
                                                  u16* __restrict__ WsM16,
                                                  float* __restrict__ attn_yT,
                                                  u16* __restrict__ imgTf) {
    int t = threadIdx.x;
    __shared__ __align__(16) u16 shu[64 * 224];   // 28.7 KB union

    // ---- phase A: k_pre tasks
    for (int task = blockIdx.x; task < 648; task += 512) {
        __syncthreads();                           // LDS WAR across stride iterations
        if (task < 512) {
            if (t < 256) sec_capnorm(task, t, cap, gloT, Qbbf, Qcap);
        } else if (task < 640) {
            sec_wt<512>(task - 512, t, shu, wi2t, wt2i, wT);
        } else if (task < 647) {
            sec_w1t<512>(task - 640, t, w1, w1Tf);
        } else {
            sec_w2t<512>(t, w2, w2Tf);
        }
    }
    cg::this_grid().sync();
    // ---- phase B: k_mid tasks
    for (int task = blockIdx.x; task < 3200; task += 512) {
        __syncthreads();
        if (task < 256)       sec_qproj(task, t, wT, bi2t, bt2i, Qcap, Qbbf);
        else if (task < 1088) sec_imgrow(task - 256, t, shu, img, w1Tf, w2Tf, gamw, betw,
                                         b1, b2, scale_p, attn_x, WsM16);
        else if (task < 2688) sec_attny(task - 1088, t, shu, img, gloT, attn_yT);
        else                  sec_imgt(task - 2688, t, shu, img, imgTf);
    }
}

// ---------------------------------------------------------------- fallback kernels (round-12 proven)
__global__ __launch_bounds__(256) void k_pre(const float* __restrict__ cap,
                                             const float* __restrict__ wi2t,
                                             const float* __restrict__ wt2i,
                                             const float* __restrict__ w1,
                                             const float* __restrict__ w2,
                                             float* __restrict__ gloT,
                                             u16* __restrict__ Qbbf,
                                             u16* __restrict__ Qcap,
                                             u16* __restrict__ wT,
                                             u16* __restrict__ w1Tf,
                                             u16* __restrict__ w2Tf) {
    int idx = blockIdx.x, t = threadIdx.x;
    __shared__ __align__(16) u16 shb[64 * 65];
    if (idx < 512) {
        sec_capnorm(idx, t, cap, gloT, Qbbf, Qcap);
    } else if (idx < 640) {
        sec_wt<256>(idx - 512, t, shb, wi2t, wt2i, wT);
    } else if (idx < 647) {
        sec_w1t<256>(idx - 640, t, w1, w1Tf);
    } else {
        sec_w2t<256>(t, w2, w2Tf);
    }
}

__global__ __launch_bounds__(512) void k_mid(const float* __restrict__ img,
                                             const u16* __restrict__ wT,
                                             const float* __restrict__ bi2t,
                                             const float* __restrict__ bt2i,
                                             const u16* __restrict__ Qcap,
                                             u16* __restrict__ Qbbf,
                                             const u16* __restrict__ w1Tf,
                                             const u16* __restrict__ w2Tf,
                                             const float* __restrict__ gamw,
                                             const float* __restrict__ betw,
                                             const float* __restrict__ b1,
                                             const float* __restrict__ b2,
                                             const float* __restrict__ scale_p,
                                             const float* __restrict__ gloT,
                                             float* __restrict__ attn_x,
                                             u16* __restrict__ WsM16,
                                             float* __restrict__ attn_yT,
                                             u16* __restrict__ imgTf) {
    int idx = blockIdx.x, t = threadIdx.x;
    __shared__ __align__(16) u16 shu[64 * 224];
    if (idx < 256)       sec_qproj(idx, t, wT, bi2t, bt2i, Qcap, Qbbf);
    else if (idx < 1088) sec_imgrow(idx - 256, t, shu, img, w1Tf, w2Tf, gamw, betw,
                                    b1, b2, scale_p, attn_x, WsM16);
    else if (idx < 2688) sec_attny(idx - 1088, t, shu, img, gloT, attn_yT);
    else                 sec_imgt(idx - 2688, t, shu, img, imgTf);
}

// ---------------------------------------------------------------- main per-pair kernel: rank + two MFMA GEMMs
__global__ __launch_bounds__(512, 4) void k_main(const float* __restrict__ attn_x,
                                                 const float* __restrict__ attn_yT,
                                                 const u16* __restrict__ WsM16,
                                                 const u16* __restrict__ imgTf,
                                                 const u16* __restrict__ Qbbf,
                                                 const float* __restrict__ temp_p,
                                                 float* __restrict__ out) {
    int lin = blockIdx.x + NCAP * blockIdx.y;     // XCD swizzle: lin%8 selects b-octet
    int b = (lin & 7) * 8 + ((lin >> 3) & 7);
    int i = lin >> 6;
    int t = threadIdx.x;
    int lane = t & 63, wu = t >> 6;
    int l15 = lane & 15, quad = lane >> 4;

    __shared__ __align__(16) u16 TnBuf[51 * 520];   // aliases Pf(51x232) then ULDS(96x52 f32)
    __shared__ float invn[64];
    __shared__ float redw[8];

    u16*   Pf   = TnBuf;
    float* ULDS = (float*)TnBuf;
    float* scoreS = (float*)(TnBuf + 24000);   // [196]
    short* rnkH   = (short*)(TnBuf + 24392);   // [2*196]
    u16*   keepL  = (u16*)  (TnBuf + 24784);   // [98]
    u16*   nonL   = (u16*)  (TnBuf + 24882);   // [98]
    float* snon   = (float*)(TnBuf + 25000);   // [98]
    float* rowsq  = (float*)(TnBuf + 25372);   // [8*64]

    const u16* imgTb = imgTf + (size_t)b * 7 * 32 * 512;
    bf16x8 Bc[4], Bn[4];
#pragma unroll
    for (int nj = 0; nj < 4; ++nj)
        Bc[nj] = ld_bf8(imgTb + (size_t)(wu * 4 + nj) * 512 + lane * 8);

    {
        uint4v* Pfv = (uint4v*)Pf;
        for (int f = t; f < 51 * 232 / 8; f += 512) Pfv[f] = (uint4v){0, 0, 0, 0};
    }
    if (t < NSP)
        scoreS[t] = attn_x[b * NSP + t] + attn_yT[((size_t)b * NCAP + i) * NSP + t];
    __syncthreads();
    if (t < 2 * NSP) {
        int half = (t >= NSP) ? 1 : 0;
        int s = t - half * NSP;
        float sv = scoreS[s];
        const float2* sc2 = (const float2*)scoreS;
        int base = half ? 49 : 0;
        int r = 0;
        for (int u2 = base; u2 < base + 49; ++u2) {
            float2 o = sc2[u2];
            int u = 2 * u2;
            r += (o.x > sv) || (o.x == sv && u < s);
            r += (o.y > sv) || (o.y == sv && (u + 1) < s);
        }
        rnkH[half * NSP + s] = (short)r;
    }
    __syncthreads();
    if (t < NSP) {
        int r = rnkH[t] + rnkH[NSP + t];
        if (r < NKEEP) keepL[r] = (u16)t;
        else { nonL[r - NKEEP] = (u16)t; snon[r - NKEEP] = scoreS[t]; }
    }
    __syncthreads();
    if (t == 0) Pf[0] = 0x3F80;                       // cls one-hot (1.0)
    if (t < NKEEP) Pf[50 * 232 + 1 + nonL[t]] = f2bf(expf(snon[t]));
    {
        int j = t / KEEPED, k = t - (t / KEEPED) * KEEPED;
#pragma unroll
        for (int it = 0; it < 10; ++it) {
            if (j < NKEEP) {
                int s = keepL[j];
                Pf[(1 + k) * 232 + 1 + s] = WsM16[((size_t)b * NSP + s) * 49 + k];
            }
            j += 10; k += 22;
            if (k >= KEEPED) { k -= KEEPED; ++j; }
        }
    }
    __syncthreads();

    f32x4 acc[4][4];
#pragma unroll
    for (int mi = 0; mi < 4; ++mi)
#pragma unroll
        for (int nj = 0; nj < 4; ++nj) acc[mi][nj] = (f32x4){0.f, 0.f, 0.f, 0.f};

    for (int ks = 0; ks < 7; ++ks) {
        if (ks < 6) {
#pragma unroll
            for (int nj = 0; nj < 4; ++nj)
                Bn[nj] = ld_bf8(imgTb + (size_t)((ks + 1) * 32 + wu * 4 + nj) * 512 + lane * 8);
        }
        bf16x8 Afr[4];
#pragma unroll
        for (int mi = 0; mi < 4; ++mi)
            Afr[mi] = ld_bf8(Pf + (mi * 16 + l15) * 232 + ks * 32 + quad * 8);
#pragma unroll
        for (int nj = 0; nj < 4; ++nj)
#pragma unroll
            for (int mi = 0; mi < 4; ++mi)
                acc[mi][nj] = __builtin_amdgcn_mfma_f32_16x16x32_bf16(Afr[mi], Bc[nj], acc[mi][nj], 0, 0, 0);
#pragma unroll
        for (int nj = 0; nj < 4; ++nj) Bc[nj] = Bn[nj];
    }

#pragma unroll
    for (int mi = 0; mi < 4; ++mi)
#pragma unroll
        for (int r = 0; r < 4; ++r) {
            float s = acc[mi][0][r] * acc[mi][0][r] + acc[mi][1][r] * acc[mi][1][r]
                    + acc[mi][2][r] * acc[mi][2][r] + acc[mi][3][r] * acc[mi][3][r];
            s += __shfl_down(s, 8); s += __shfl_down(s, 4);
            s += __shfl_down(s, 2); s += __shfl_down(s, 1);
            if (l15 == 0) rowsq[wu * 64 + mi * 16 + quad * 4 + r] = s;
        }
    __syncthreads();
    if (t < 64) {
        float s = 0.f;
#pragma unroll
        for (int w2 = 0; w2 < 8; ++w2) s += rowsq[w2 * 64 + t];
        invn[t] = 1.f / fmaxf(sqrtf(s), 1e-12f);
    }
    __syncthreads();

#pragma unroll
    for (int mi = 0; mi < 4; ++mi)
#pragma unroll
        for (int r = 0; r < 4; ++r) {
            int row = mi * 16 + quad * 4 + r;
            if (row < 51) {
                float iv = invn[row];
#pragma unroll
                for (int nj = 0; nj < 4; ++nj)
                    TnBuf[row * 520 + (wu * 4 + nj) * 16 + l15] = f2bf(acc[mi][nj][r] * iv);
            }
        }
    __syncthreads();

    const u16* Qbf = Qbbf + (size_t)i * 6 * 16 * 512;
    f32x4 ua[3];
#pragma unroll
    for (int e = 0; e < 3; ++e) ua[e] = (f32x4){0.f, 0.f, 0.f, 0.f};

    if (wu < 6) {
        const u16* Ar = Qbf + (size_t)wu * 16 * 512 + lane * 8;
        bf16x8 Aa = ld_bf8(Ar + 0 * 512);
        bf16x8 Ab = ld_bf8(Ar + 1 * 512);
        bf16x8 Ac = ld_bf8(Ar + 2 * 512);
        bf16x8 Ad = ld_bf8(Ar + 3 * 512);
#pragma unroll
        for (int g = 0; g < 4; ++g) {
            bf16x8 Na, Nb, Nc, Nd;
            if (g < 3) {
                Na = ld_bf8(Ar + (g * 4 + 4) * 512);
                Nb = ld_bf8(Ar + (g * 4 + 5) * 512);
                Nc = ld_bf8(Ar + (g * 4 + 6) * 512);
                Nd = ld_bf8(Ar + (g * 4 + 7) * 512);
            }
#pragma unroll
            for (int e = 0; e < 3; ++e) {
                const u16* Tb = TnBuf + (e * 16 + l15) * 520 + quad * 8;
                ua[e] = __builtin_amdgcn_mfma_f32_16x16x32_bf16(Aa, ld_bf8(Tb + (g * 4 + 0) * 32), ua[e], 0, 0, 0);
                ua[e] = __builtin_amdgcn_mfma_f32_16x16x32_bf16(Ab, ld_bf8(Tb + (g * 4 + 1) * 32), ua[e], 0, 0, 0);
                ua[e] = __builtin_amdgcn_mfma_f32_16x16x32_bf16(Ac, ld_bf8(Tb + (g * 4 + 2) * 32), ua[e], 0, 0, 0);
                ua[e] = __builtin_amdgcn_mfma_f32_16x16x32_bf16(Ad, ld_bf8(Tb + (g * 4 + 3) * 32), ua[e], 0, 0, 0);
            }
            Aa = Na; Ab = Nb; Ac = Nc; Ad = Nd;
        }
    } else {
        int w2 = wu - 6;
        int rowB = 48 + l15; if (rowB > 50) rowB = 50;
        const u16* Ar0 = Qbf + (size_t)(3 * w2 + 0) * 16 * 512 + lane * 8;
        const u16* Ar1 = Qbf + (size_t)(3 * w2 + 1) * 16 * 512 + lane * 8;
        const u16* Ar2 = Qbf + (size_t)(3 * w2 + 2) * 16 * 512 + lane * 8;
        bf16x8 Af0 = ld_bf8(Ar0);
        bf16x8 Af1 = ld_bf8(Ar1);
        bf16x8 Af2 = ld_bf8(Ar2);
        for (int ks = 0; ks < 16; ++ks) {
            bf16x8 An0, An1, An2;
            if (ks < 15) {
                An0 = ld_bf8(Ar0 + (ks + 1) * 512);
                An1 = ld_bf8(Ar1 + (ks + 1) * 512);
                An2 = ld_bf8(Ar2 + (ks + 1) * 512);
            }
            bf16x8 Bf = ld_bf8(TnBuf + rowB * 520 + ks * 32 + quad * 8);
            ua[0] = __builtin_amdgcn_mfma_f32_16x16x32_bf16(Af0, Bf, ua[0], 0, 0, 0);
            ua[1] = __builtin_amdgcn_mfma_f32_16x16x32_bf16(Af1, Bf, ua[1], 0, 0, 0);
            ua[2] = __builtin_amdgcn_mfma_f32_16x16x32_bf16(Af2, Bf, ua[2], 0, 0, 0);
            Af0 = An0; Af1 = An1; Af2 = An2;
        }
    }
    __syncthreads();

    if (wu < 6) {
#pragma unroll
        for (int e = 0; e < 3; ++e) {
            int l = e * 16 + l15;
            int q0 = wu * 16 + quad * 4;
#pragma unroll
            for (int r = 0; r < 4; ++r) ULDS[(q0 + r) * 52 + l] = ua[e][r];
        }
    } else {
        int l = 48 + l15;
        if (l < 51) {
            int w2 = wu - 6;
#pragma unroll
            for (int e = 0; e < 3; ++e) {
                int q0 = (3 * w2 + e) * 16 + quad * 4;
#pragma unroll
                for (int r = 0; r < 4; ++r) ULDS[(q0 + r) * 52 + l] = ua[e][r];
            }
        }
    }
    __syncthreads();

    float invT = 1.f / temp_p[0];
    if (t < 408) {
        int l = t >> 3, sub = t & 7;
        float vbuf[4]; float mm = -1e30f;
#pragma unroll
        for (int q = 0; q < 4; ++q) {
            float v = ULDS[(32 + sub + 8 * q) * 52 + l] * invT;
            vbuf[q] = v;
            mm = fmaxf(mm, v);
        }
#pragma unroll
        for (int o = 1; o < 8; o <<= 1) mm = fmaxf(mm, __shfl_xor(mm, o, 8));
        float e[4]; float z = 0.f;
#pragma unroll
        for (int q = 0; q < 4; ++q) { e[q] = expf(vbuf[q] - mm); z += e[q]; }
#pragma unroll
        for (int o = 1; o < 8; o <<= 1) z += __shfl_xor(z, o, 8);
        float iz = 1.f / z;
#pragma unroll
        for (int q = 0; q < 4; ++q) ULDS[(32 + sub + 8 * q) * 52 + l] = e[q] * iz;
    }
    if (t < 256) {
        int u = t >> 3, sub = t & 7;
        float vbuf[7]; int cnt = 0; float mm = -1e30f;
        for (int l = sub; l < 51; l += 8) {
            float v = ULDS[(64 + u) * 52 + l] * invT;
            vbuf[cnt++] = v;
            mm = fmaxf(mm, v);
        }
#pragma unroll
        for (int o = 1; o < 8; o <<= 1) mm = fmaxf(mm, __shfl_xor(mm, o, 8));
        float e[7]; float z = 0.f;
        for (int q = 0; q < cnt; ++q) { e[q] = expf(vbuf[q] - mm); z += e[q]; }
#pragma unroll
        for (int o = 1; o < 8; o <<= 1) z += __shfl_xor(z, o, 8);
        float iz = 1.f / z;
        { int q = 0;
          for (int l = sub; l < 51; l += 8) { ULDS[(64 + u) * 52 + l] = e[q] * iz; ++q; } }
    }
    __syncthreads();

    float part = 0.f;
    {
        int u = t / 51, l = t - (t / 51) * 51;
        while (u < LT) {
            float u0 = ULDS[u * 52 + l];
            float c2 = (u0 > 0.f) ? u0 : 0.1f * u0;
            float av = ULDS[(32 + u) * 52 + l];
            float bv = ULDS[(64 + u) * 52 + l];
            part += c2 * (av * (1.f / 51.f) + bv * (1.f / 32.f));
            u += 10; l += 2;
            if (l >= 51) { l -= 51; ++u; }
        }
    }
    for (int o = 32; o > 0; o >>= 1) part += __shfl_down(part, o);
    if (lane == 0) redw[wu] = part;
    __syncthreads();
    if (t == 0) {
        float s = 0.f;
#pragma unroll
        for (int w2 = 0; w2 < 8; ++w2) s += redw[w2];
        out[b * NCAP + i] = s;
    }
}

extern "C" void kernel_launch(void* const* d_in, const int* in_sizes, int n_in,
                              void* d_out, int out_size, void* d_ws, size_t ws_size,
                              hipStream_t stream) {
    const float* img        = (const float*)d_in[0];
    const float* cap        = (const float*)d_in[1];
    const float* gamw       = (const float*)d_in[3];
    const float* betw       = (const float*)d_in[4];
    const float* w1         = (const float*)d_in[5];
    const float* b1         = (const float*)d_in[6];
    const float* w2         = (const float*)d_in[7];
    const float* b2         = (const float*)d_in[8];
    const float* aggr_scale = (const float*)d_in[9];
    const float* wi2t       = (const float*)d_in[10];
    const float* bi2t       = (const float*)d_in[11];
    const float* wt2i       = (const float*)d_in[12];
    const float* bt2i       = (const float*)d_in[13];
    const float* temp       = (const float*)d_in[14];
    float* out = (float*)d_out;

    float* ws      = (float*)d_ws;
    float* attn_x  = ws + OFF_ATTNX;
    u16*   WsM16   = (u16*)(ws + OFF_WSMAT);
    u16*   wT      = (u16*)(ws + OFF_WT);
    float* gloT    = ws + OFF_GLOT;
    float* attn_yT = ws + OFF_ATTNYT;
    u16*   imgTf   = (u16*)(ws + OFF_IMGT);
    u16*   Qbbf    = (u16*)(ws + OFF_QBB);
    u16*   Qcap    = (u16*)(ws + OFF_QCAP);
    u16*   w1Tf    = (u16*)(ws + OFF_W1TF);
    u16*   w2Tf    = (u16*)(ws + OFF_W2TF);

    // cooperative fused k_pre+k_mid (one launch boundary removed); fallback = round-12 pair
    void* fargs[] = {
        (void*)&img, (void*)&cap, (void*)&wi2t, (void*)&wt2i, (void*)&w1, (void*)&w2,
        (void*)&bi2t, (void*)&bt2i, (void*)&gamw, (void*)&betw, (void*)&b1, (void*)&b2,
        (void*)&aggr_scale, (void*)&gloT, (void*)&Qbbf, (void*)&Qcap, (void*)&wT,
        (void*)&w1Tf, (void*)&w2Tf, (void*)&attn_x, (void*)&WsM16, (void*)&attn_yT,
        (void*)&imgTf
    };
    hipError_t cerr = hipLaunchCooperativeKernel((const void*)k_fused, dim3(512), dim3(512),
                                                 fargs, 0, stream);
    if (cerr != hipSuccess) {
        k_pre<<<dim3(648), dim3(256), 0, stream>>>(cap, wi2t, wt2i, w1, w2,
                                                   gloT, Qbbf, Qcap, wT, w1Tf, w2Tf);
        k_mid<<<dim3(3200), dim3(512), 0, stream>>>(img, wT, bi2t, bt2i, Qcap, Qbbf,
                                                    w1Tf, w2Tf, gamw, betw, b1, b2, aggr_scale,
                                                    gloT, attn_x, WsM16, attn_yT, imgTf);
    }
    k_main<<<dim3(NCAP, B), dim3(512), 0, stream>>>(attn_x, attn_yT, WsM16, imgTf, Qbbf, temp, out);
}

// Round 16
// 341.119 us; speedup vs baseline: 1.4753x; 1.4753x over previous
//
#include <hip/hip_runtime.h>
#include <math.h>

#define B     64
#define NCAP  64
#define LV    197
#define LT    32
#define C     512
#define NSP   196
#define NKEEP 98
#define HID   102
#define KEEPED 49

// Workspace layout (float element offsets). Total ~80 MB (< proven 106.8 MB).
#define OFF_ATTNX   12608                     // B*NSP
#define OFF_WSMAT   25152                     // u16 B*NSP*KEEPED (holds bf16 exp(Ws))
#define OFF_WT      639808                    // u16 2*512*512 (bf16 wi2t^T / wt2i^T)
#define OFF_GLOT    1688384                   // C*NCAP  (packed float4: [c/4][i][4])
#define OFF_ATTNYT  1721152                   // 4096*196 floats (transposed [b][i][s])
#define OFF_IMGT    14164800                  // u16 64*7*32*512 fragment-major imgT
#define OFF_QBB     17834816                  // u16 64*6*16*512 fragment-major Qbb
#define OFF_QCAP    19407680                  // u16 64*32*512 row-major cap rows (qproj input)
#define OFF_W1TF    19931968                  // u16 7*16*512 fragment-major w1^T (N=112 pad, K=512)
#define OFF_W2TF    19960640                  // u16 4*4*512 fragment-major w2^T (N=64 pad, K=128 pad)

typedef unsigned int u32;
typedef unsigned short u16;
typedef __bf16 bf16x8 __attribute__((ext_vector_type(8)));
typedef float f32x4 __attribute__((ext_vector_type(4)));
typedef unsigned int uint4v __attribute__((ext_vector_type(4)));

__device__ __forceinline__ u16 f2bf(float f) {
    u32 u = __builtin_bit_cast(u32, f);
    return (u16)((u + 0x7FFFu + ((u >> 16) & 1u)) >> 16);
}
__device__ __forceinline__ bf16x8 ld_bf8(const u16* p) {
    uint4v v = *reinterpret_cast<const uint4v*>(p);
    return __builtin_bit_cast(bf16x8, v);
}

__device__ __forceinline__ float gelu_exact(float x) {
    return 0.5f * x * (1.f + erff(x * 0.70710678118654752f));
}

// ---------------------------------------------------------------- k_pre (648 blocks, 256 thr):
// cap_norm (0..511) | wt (512..639) | w1t (640..646) | w2t (647)
__global__ __launch_bounds__(256) void k_pre(const float* __restrict__ cap,
                                             const float* __restrict__ wi2t,
                                             const float* __restrict__ wt2i,
                                             const float* __restrict__ w1,
                                             const float* __restrict__ w2,
                                             float* __restrict__ gloT,
                                             u16* __restrict__ Qbbf,
                                             u16* __restrict__ Qcap,
                                             u16* __restrict__ wT,
                                             u16* __restrict__ w1Tf,
                                             u16* __restrict__ w2Tf) {
    int idx = blockIdx.x, t = threadIdx.x;
    __shared__ __align__(16) u16 shb[64 * 65];     // 8.3 KB (wt tile)

    if (idx < 512) {
        // ---- caption norms, 4 rows/block
        int e = idx, i = e >> 3, tg = e & 7;
        int lane = t & 63, wv = t >> 6;
        int tt = tg * 4 + wv;
        const float* row = cap + ((size_t)i * LT + tt) * C;
        float v[8]; float ss = 0.f;
#pragma unroll
        for (int q = 0; q < 8; ++q) { v[q] = row[lane + 64 * q]; ss += v[q] * v[q]; }
        for (int o = 32; o > 0; o >>= 1) ss += __shfl_down(ss, o);
        ss = __shfl(ss, 0);
        float inv = 1.f / fmaxf(sqrtf(ss), 1e-12f);
        u16* qrow = Qcap + ((size_t)i * 32 + tt) * C;
        int mi = tt >> 4, l15f = tt & 15;
        u16* qfb = Qbbf + (size_t)(i * 6 + mi) * 16 * 512;
#pragma unroll
        for (int q = 0; q < 8; ++q) {
            float n = v[q] * inv;
            u16 nb = f2bf(n);
            int c = lane + 64 * q;
            qrow[c] = nb;
            int ks = c >> 5, quadf = (c >> 3) & 3, jf = c & 7;
            qfb[(size_t)ks * 512 + (quadf * 16 + l15f) * 8 + jf] = nb;
            // packed float4 layout for attn_y: gloT4[c/4][i][c%4]
            if (tt == 0) gloT[(c >> 2) * (NCAP * 4) + i * 4 + (c & 3)] = n;
        }
    } else if (idx < 640) {
        // ---- transpose wi2t/wt2i -> bf16 [j][c], one 64x64 tile per block
        int e = idx - 512;
        int mat = e >> 6, ty = e & 63, jg = ty >> 3, cg = ty & 7;
        const float* W = mat ? wt2i : wi2t;
        u16 (*tile)[65] = (u16(*)[65])shb;
        for (int f = t; f < 4096; f += 256) {
            int cc2 = f >> 6, jj = f & 63;
            tile[jj][cc2] = f2bf(W[(size_t)(cg * 64 + cc2) * 512 + jg * 64 + jj]);
        }
        __syncthreads();
        for (int f = t; f < 4096; f += 256) {
            int jj = f >> 6, cc2 = f & 63;
            wT[((size_t)mat * 512 + jg * 64 + jj) * 512 + cg * 64 + cc2] = tile[jj][cc2];
        }
    } else if (idx < 647) {
        // ---- w1^T fragment-major: B[n=j][kk=c] = w1[c][j]; N-tile nt, 16 K-tiles
        int nt = idx - 640;
        u32* outp = (u32*)w1Tf + (size_t)nt * 16 * 256;
        for (int f = t; f < 16 * 256; f += 256) {
            int ks = f >> 8, g = f & 255;
            int lane_o = g >> 2, j2 = g & 3;
            int l15o = lane_o & 15, quado = lane_o >> 4;
            int kk = ks * 32 + quado * 8 + 2 * j2;
            int n = nt * 16 + l15o;
            u32 lo = 0, hi = 0;
            if (n < HID) {
                lo = f2bf(w1[(size_t)kk * HID + n]);
                hi = f2bf(w1[(size_t)(kk + 1) * HID + n]);
            }
            outp[ks * 256 + g] = lo | (hi << 16);
        }
    } else {
        // ---- w2^T fragment-major: B[n=k][kk=h] = w2[h][k]; tiles [nt2(4)][ks2(4)]
        u32* outp = (u32*)w2Tf;
        for (int f = t; f < 16 * 256; f += 256) {
            int tile = f >> 8, g = f & 255;
            int nt2 = tile >> 2, ks2 = tile & 3;
            int lane_o = g >> 2, j2 = g & 3;
            int l15o = lane_o & 15, quado = lane_o >> 4;
            int kk0 = ks2 * 32 + quado * 8 + 2 * j2;
            int n = nt2 * 16 + l15o;
            u32 lo = 0, hi = 0;
            if (n < KEEPED) {
                if (kk0 < HID)     lo = f2bf(w2[(size_t)kk0 * KEEPED + n]);
                if (kk0 + 1 < HID) hi = f2bf(w2[(size_t)(kk0 + 1) * KEEPED + n]);
            }
            outp[tile * 256 + g] = lo | (hi << 16);
        }
    }
}

// ---------------------------------------------------------------- k_mid (3200 blocks, 512 thr):
// qproj (0..255) | img_row MFMA (256..1087) | attn_y (1088..2687) | imgT-frag (2688..3199)
// attn_y reads gloT (written by k_pre) — must stay in this second launch (round-13 race lesson).
__global__ __launch_bounds__(512) void k_mid(const float* __restrict__ img,
                                             const u16* __restrict__ wT,
                                             const float* __restrict__ bi2t,
                                             const float* __restrict__ bt2i,
                                             const u16* __restrict__ Qcap,
                                             u16* __restrict__ Qbbf,
                                             const u16* __restrict__ w1Tf,
                                             const u16* __restrict__ w2Tf,
                                             const float* __restrict__ gamw,
                                             const float* __restrict__ betw,
                                             const float* __restrict__ b1,
                                             const float* __restrict__ b2,
                                             const float* __restrict__ scale_p,
                                             const float* __restrict__ gloT,
                                             float* __restrict__ attn_x,
                                             u16* __restrict__ WsM16,
                                             float* __restrict__ attn_yT,
                                             u16* __restrict__ imgTf) {
    int idx = blockIdx.x, t = threadIdx.x;
    __shared__ __align__(16) u16 shu[64 * 224];   // 28.7 KB union (imgT shb | LNb+Hb | xr)

    if (idx < 256) {
        // ---- qi2t/qt2i via MFMA (A/B prefetch); output into fragment-major Qbbf
        int i = idx & 63, p = idx >> 6;
        int lane = t & 63, wu = t >> 6;
        int l15 = lane & 15, quad = lane >> 4;
        int mat = wu >> 2;
        int miq = (wu >> 1) & 1;
        int nh  = wu & 1;
        int ni0 = p * 8 + nh * 4;
        const u16* Arow = Qcap + ((size_t)i * 32 + miq * 16 + l15) * 512;
        const u16* Wm   = wT + (size_t)mat * 512 * 512;
        f32x4 acc[4];
#pragma unroll
        for (int n = 0; n < 4; ++n) acc[n] = (f32x4){0.f, 0.f, 0.f, 0.f};
        bf16x8 A = ld_bf8(Arow + quad * 8);
        bf16x8 Bf[4];
#pragma unroll
        for (int n = 0; n < 4; ++n)
            Bf[n] = ld_bf8(Wm + (size_t)((ni0 + n) * 16 + l15) * 512 + quad * 8);
        for (int ks = 0; ks < 16; ++ks) {
            bf16x8 An; bf16x8 Bn[4];
            if (ks < 15) {
                An = ld_bf8(Arow + (ks + 1) * 32 + quad * 8);
#pragma unroll
                for (int n = 0; n < 4; ++n)
                    Bn[n] = ld_bf8(Wm + (size_t)((ni0 + n) * 16 + l15) * 512 + (ks + 1) * 32 + quad * 8);
            }
#pragma unroll
            for (int n = 0; n < 4; ++n)
                acc[n] = __builtin_amdgcn_mfma_f32_16x16x32_bf16(A, Bf[n], acc[n], 0, 0, 0);
            A = An;
#pragma unroll
            for (int n = 0; n < 4; ++n) Bf[n] = Bn[n];
        }
        const float* bias = mat ? bt2i : bi2t;
#pragma unroll
        for (int n = 0; n < 4; ++n) {
            int j = (ni0 + n) * 16 + l15;
            float bj = bias[j];
            int ksf = j >> 5, quadf = (j >> 3) & 3, jf = j & 7;
#pragma unroll
            for (int r = 0; r < 4; ++r) {
                int q = 32 + mat * 32 + miq * 16 + quad * 4 + r;
                int mi = q >> 4, l15f = q & 15;
                Qbbf[(size_t)((i * 6 + mi) * 16 + ksf) * 512 + (quadf * 16 + l15f) * 8 + jf]
                    = f2bf(acc[n][r] + bj);
            }
        }
    } else if (idx < 1088) {
        // ---- img_row via MFMA: 16 s-rows/block, LN+attn_x fp32, two bf16 GEMMs
        int e = idx - 256;
        int b = e / 13, sg = e - b * 13;
        int s0 = sg * 16;
        u16* LNb = shu;              // [16][520]
        u16* Hb  = shu + 16 * 520;   // [16][136]
        int lane = t & 63, wu = t >> 6;
        int l15 = lane & 15, quad = lane >> 4;

        // Phase A: wave wu owns rows 2wu, 2wu+1 — stats in registers, attn_x bit-identical fp32
        {
            int rr0 = 2 * wu, rr1 = 2 * wu + 1;
            int sA = s0 + rr0, sB = s0 + rr1;
            int sAc = sA < NSP ? sA : NSP - 1;
            int sBc = sB < NSP ? sB : NSP - 1;
            const float* rowA = img + ((size_t)b * LV + 1 + sAc) * C;
            const float* rowB = img + ((size_t)b * LV + 1 + sBc) * C;
            const float* cls  = img + (size_t)b * LV * C;
            float v0[8], v1[8];
            float sm0 = 0, ss0 = 0, dd0 = 0, sm1 = 0, ss1 = 0, dd1 = 0, sc = 0;
#pragma unroll
            for (int q = 0; q < 8; ++q) {
                int c = lane + 64 * q;
                float cv = cls[c];
                v0[q] = rowA[c]; v1[q] = rowB[c];
                sm0 += v0[q]; ss0 += v0[q] * v0[q]; dd0 += v0[q] * cv;
                sm1 += v1[q]; ss1 += v1[q] * v1[q]; dd1 += v1[q] * cv;
                sc  += cv * cv;
            }
            for (int o = 32; o > 0; o >>= 1) {
                sm0 += __shfl_down(sm0, o); ss0 += __shfl_down(ss0, o); dd0 += __shfl_down(dd0, o);
                sm1 += __shfl_down(sm1, o); ss1 += __shfl_down(ss1, o); dd1 += __shfl_down(dd1, o);
                sc  += __shfl_down(sc, o);
            }
            sm0 = __shfl(sm0, 0); ss0 = __shfl(ss0, 0);
            sm1 = __shfl(sm1, 0); ss1 = __shfl(ss1, 0);
            float mean0 = sm0 * (1.f / C);
            float rstd0 = 1.f / sqrtf(ss0 * (1.f / C) - mean0 * mean0 + 1e-5f);
            float mean1 = sm1 * (1.f / C);
            float rstd1 = 1.f / sqrtf(ss1 * (1.f / C) - mean1 * mean1 + 1e-5f);
            if (lane == 0) {
                float inv0 = 1.f / fmaxf(sqrtf(sc), 1e-12f);
                if (sA < NSP) attn_x[b * NSP + sA] = dd0 * inv0 * (1.f / fmaxf(sqrtf(ss0), 1e-12f));
                if (sB < NSP) attn_x[b * NSP + sB] = dd1 * inv0 * (1.f / fmaxf(sqrtf(ss1), 1e-12f));
            }
#pragma unroll
            for (int q = 0; q < 8; ++q) {
                int c = lane + 64 * q;
                float g = gamw[c], be = betw[c];
                LNb[rr0 * 520 + c] = f2bf((v0[q] - mean0) * rstd0 * g + be);
                LNb[rr1 * 520 + c] = f2bf((v1[q] - mean1) * rstd1 * g + be);
            }
        }
        __syncthreads();
        // GEMM-1: h = ln @ w1 (wave wu<7 owns N-tile wu); wave 7 zeros Hb K-pad cols
        if (wu < 7) {
            const u16* W1b = w1Tf + (size_t)wu * 16 * 512;
            f32x4 h4 = (f32x4){0.f, 0.f, 0.f, 0.f};
            for (int ks = 0; ks < 16; ++ks) {
                bf16x8 A = ld_bf8(LNb + l15 * 520 + ks * 32 + quad * 8);
                bf16x8 Bv = ld_bf8(W1b + ks * 512 + lane * 8);
                h4 = __builtin_amdgcn_mfma_f32_16x16x32_bf16(A, Bv, h4, 0, 0, 0);
            }
            int col = wu * 16 + l15;
            if (col < HID) {
                float bb = b1[col];
#pragma unroll
                for (int r = 0; r < 4; ++r)
                    Hb[(quad * 4 + r) * 136 + col] = f2bf(gelu_exact(h4[r] + bb));
            } else {
#pragma unroll
                for (int r = 0; r < 4; ++r) Hb[(quad * 4 + r) * 136 + col] = 0;
            }
        } else {
            for (int f = lane; f < 16 * 24; f += 64) {
                int row = f / 24, cc = 112 + f % 24;
                Hb[row * 136 + cc] = 0;
            }
        }
        __syncthreads();
        // GEMM-2: Ws = gelu(h) @ w2 (waves 0..3 own N-tiles). Store bf16(exp(Ws)) —
        // f2bf hoisted here so k_main's scatter is a raw u16 copy.
        if (wu < 4) {
            const u16* W2b = w2Tf + (size_t)wu * 4 * 512;
            f32x4 a2 = (f32x4){0.f, 0.f, 0.f, 0.f};
            for (int ks2 = 0; ks2 < 4; ++ks2) {
                bf16x8 A2 = ld_bf8(Hb + l15 * 136 + ks2 * 32 + quad * 8);
                bf16x8 B2 = ld_bf8(W2b + ks2 * 512 + lane * 8);
                a2 = __builtin_amdgcn_mfma_f32_16x16x32_bf16(A2, B2, a2, 0, 0, 0);
            }
            int k = wu * 16 + l15;
            if (k < KEEPED) {
                float scale = scale_p[0], bk = b2[k];
#pragma unroll
                for (int r = 0; r < 4; ++r) {
                    int row = quad * 4 + r;
                    if (s0 + row < NSP)
                        WsM16[((size_t)b * NSP + s0 + row) * 49 + k] = f2bf(expf((a2[r] + bk) * scale));
                }
            }
        }
    } else if (idx < 2688) {
        // ---- attn_y transposed, 8 rows/block, wave w owns row w (fp32 — score precision)
        int e = idx - 1088;
        int b = e / 25;
        int s0 = (e - b * 25) * 8;
        int R = NSP - s0; if (R > 8) R = 8;
        float (*xr)[C] = (float(*)[C])shu;     // 16 KB overlay
        float* rnorm = (float*)shu + 4096;

        for (int f = t; f < R * C; f += 512) {
            int rr = f >> 9, c = f & 511;
            xr[rr][c] = img[((size_t)b * LV + 1 + s0 + rr) * C + c];
        }
        __syncthreads();
        {
            int row = t >> 6, l = t & 63;
            if (row < R) {
                float ss = 0.f;
                for (int c = l; c < C; c += 64) { float v = xr[row][c]; ss += v * v; }
                for (int o = 32; o > 0; o >>= 1) ss += __shfl_down(ss, o);
                if (l == 0) rnorm[row] = 1.f / fmaxf(sqrtf(ss), 1e-12f);
            }
        }
        __syncthreads();
        for (int f = t; f < R * C; f += 512) {
            int rr = f >> 9, c = f & 511;
            xr[rr][c] *= rnorm[rr];
        }
        __syncthreads();
        int i = t & 63, w = t >> 6;
        if (w < R) {
            float a0 = 0.f;
            const float4* g4 = (const float4*)gloT;   // packed [c4][i][4]
            const float4* x4 = (const float4*)xr[w];
            for (int c4 = 0; c4 < C / 4; ++c4) {
                float4 g = g4[c4 * NCAP + i];
                float4 x0 = x4[c4];
                a0 += x0.x * g.x + x0.y * g.y + x0.z * g.z + x0.w * g.w;
            }
            attn_yT[((size_t)b * NCAP + i) * NSP + s0 + w] = a0;
        }
    } else {
        // ---- imgT fragment-major (512-thread restride, same element map)
        int e = idx - 2688;
        int b = e >> 3, cg = e & 7;
        for (int f = t; f < 64 * 27; f += 512) shu[(f / 27) * 224 + 197 + (f % 27)] = 0;
        int cc = t & 63;
        for (int sb = t >> 6; sb < 197; sb += 8) {
            float v = img[((size_t)b * LV + sb) * C + cg * 64 + cc];
            shu[cc * 224 + sb] = f2bf(v);
        }
        __syncthreads();
        const u32* Tu = (const u32*)shu;
        u32* outp = (u32*)imgTf + (size_t)b * 7 * 32 * 256;
        for (int f = t; f < 7 * 4 * 256; f += 512) {
            int ks = f >> 10, rem = f & 1023;
            int ctl = rem >> 8, g = rem & 255;
            int lane_o = g >> 2, j2 = g & 3;
            int quad_o = lane_o >> 4, l15_o = lane_o & 15;
            int ccl = ctl * 16 + l15_o;
            int s = ks * 32 + quad_o * 8 + 2 * j2;
            u32 v = Tu[ccl * 112 + (s >> 1)];
            outp[(size_t)(ks * 32 + cg * 4 + ctl) * 256 + g] = v;
        }
    }
}

// ---------------------------------------------------------------- main per-pair kernel: rank + two MFMA GEMMs
// 3-launch structure + in-chain cheapeners: u16 WsM16 scatter, early-B issue,
// fixed-10 scatter unroll, depth-4 phase-2 prefetch (VGPR-neutral, r9).
__global__ __launch_bounds__(512, 4) void k_main(const float* __restrict__ attn_x,
                                                 const float* __restrict__ attn_yT,
                                                 const u16* __restrict__ WsM16,
                                                 const u16* __restrict__ imgTf,
                                                 const u16* __restrict__ Qbbf,
                                                 const float* __restrict__ temp_p,
                                                 float* __restrict__ out) {
    int lin = blockIdx.x + NCAP * blockIdx.y;     // XCD swizzle: lin%8 selects b-octet
    int b = (lin & 7) * 8 + ((lin >> 3) & 7);
    int i = lin >> 6;
    int t = threadIdx.x;
    int lane = t & 63, wu = t >> 6;
    int l15 = lane & 15, quad = lane >> 4;

    __shared__ __align__(16) u16 TnBuf[51 * 520];   // aliases Pf(51x232) then ULDS(96x52 f32)
    __shared__ float invn[64];                       // live during Tn writes — NOT aliased
    __shared__ float redw[8];                        // live during ULDS epilogue — NOT aliased

    u16*   Pf   = TnBuf;
    float* ULDS = (float*)TnBuf;
    // ---- aliased scratch in TnBuf tail (Pf zero touches u16 0..11831; zone 24000+ untouched):
    //      all dead before the Tn-write phase (round-4 verified liveness).
    float* scoreS = (float*)(TnBuf + 24000);   // [196]
    short* rnkH   = (short*)(TnBuf + 24392);   // [2*196]
    u16*   keepL  = (u16*)  (TnBuf + 24784);   // [98]
    u16*   nonL   = (u16*)  (TnBuf + 24882);   // [98]
    float* snon   = (float*)(TnBuf + 25000);   // [98] (byte 50000, 4-aligned)
    float* rowsq  = (float*)(TnBuf + 25372);   // [8*64] (dead before Tn write)

    // ---- early-issue phase-1 B fragments (only need b; latency hides under prologue)
    const u16* imgTb = imgTf + (size_t)b * 7 * 32 * 512;
    bf16x8 Bc[4], Bn[4];
#pragma unroll
    for (int nj = 0; nj < 4; ++nj)
        Bc[nj] = ld_bf8(imgTb + (size_t)(wu * 4 + nj) * 512 + lane * 8);

    // ---- 1. zero Pf rows 0..50 (16B stores) + load scores
    {
        uint4v* Pfv = (uint4v*)Pf;
        for (int f = t; f < 51 * 232 / 8; f += 512) Pfv[f] = (uint4v){0, 0, 0, 0};
    }
    if (t < NSP)
        scoreS[t] = attn_x[b * NSP + t] + attn_yT[((size_t)b * NCAP + i) * NSP + t];
    __syncthreads();
    // ---- 2. stable-descending rank, split over 392 threads (float2 broadcast reads)
    if (t < 2 * NSP) {
        int half = (t >= NSP) ? 1 : 0;
        int s = t - half * NSP;
        float sv = scoreS[s];
        const float2* sc2 = (const float2*)scoreS;
        int base = half ? 49 : 0;
        int r = 0;
        for (int u2 = base; u2 < base + 49; ++u2) {
            float2 o = sc2[u2];
            int u = 2 * u2;
            r += (o.x > sv) || (o.x == sv && u < s);
            r += (o.y > sv) || (o.y == sv && (u + 1) < s);
        }
        rnkH[half * NSP + s] = (short)r;
    }
    __syncthreads();
    if (t < NSP) {
        int r = rnkH[t] + rnkH[NSP + t];
        if (r < NKEEP) keepL[r] = (u16)t;
        else { nonL[r - NKEEP] = (u16)t; snon[r - NKEEP] = scoreS[t]; }
    }
    __syncthreads();
    // ---- 3. scatter P into Pf (WsM16 holds bf16 exp(Ws) — raw u16 copy); fixed-10 unroll
    if (t == 0) Pf[0] = 0x3F80;                       // cls one-hot (1.0)
    if (t < NKEEP) Pf[50 * 232 + 1 + nonL[t]] = f2bf(expf(snon[t]));
    {
        int j = t / KEEPED, k = t - (t / KEEPED) * KEEPED;
#pragma unroll
        for (int it = 0; it < 10; ++it) {
            if (j < NKEEP) {
                int s = keepL[j];
                Pf[(1 + k) * 232 + 1 + s] = WsM16[((size_t)b * NSP + s) * 49 + k];
            }
            j += 10; k += 22;                          // += 512 = 10*49 + 22
            if (k >= KEEPED) { k -= KEEPED; ++j; }
        }
    }
    __syncthreads();

    // ---- phase 1: T(51x512) = Pfull @ imgT ; wave w owns ct range [4w, 4w+4)
    f32x4 acc[4][4];
#pragma unroll
    for (int mi = 0; mi < 4; ++mi)
#pragma unroll
        for (int nj = 0; nj < 4; ++nj) acc[mi][nj] = (f32x4){0.f, 0.f, 0.f, 0.f};

    for (int ks = 0; ks < 7; ++ks) {
        if (ks < 6) {
#pragma unroll
            for (int nj = 0; nj < 4; ++nj)
                Bn[nj] = ld_bf8(imgTb + (size_t)((ks + 1) * 32 + wu * 4 + nj) * 512 + lane * 8);
        }
        bf16x8 Afr[4];
#pragma unroll
        for (int mi = 0; mi < 4; ++mi)
            Afr[mi] = ld_bf8(Pf + (mi * 16 + l15) * 232 + ks * 32 + quad * 8);
#pragma unroll
        for (int nj = 0; nj < 4; ++nj)
#pragma unroll
            for (int mi = 0; mi < 4; ++mi)
                acc[mi][nj] = __builtin_amdgcn_mfma_f32_16x16x32_bf16(Afr[mi], Bc[nj], acc[mi][nj], 0, 0, 0);
#pragma unroll
        for (int nj = 0; nj < 4; ++nj) Bc[nj] = Bn[nj];
    }

    // ---- row sums of squares (rowsq in alias zone: dead before Tn write)
#pragma unroll
    for (int mi = 0; mi < 4; ++mi)
#pragma unroll
        for (int r = 0; r < 4; ++r) {
            float s = acc[mi][0][r] * acc[mi][0][r] + acc[mi][1][r] * acc[mi][1][r]
                    + acc[mi][2][r] * acc[mi][2][r] + acc[mi][3][r] * acc[mi][3][r];
            s += __shfl_down(s, 8); s += __shfl_down(s, 4);
            s += __shfl_down(s, 2); s += __shfl_down(s, 1);
            if (l15 == 0) rowsq[wu * 64 + mi * 16 + quad * 4 + r] = s;
        }
    __syncthreads();
    if (t < 64) {
        float s = 0.f;
#pragma unroll
        for (int w2 = 0; w2 < 8; ++w2) s += rowsq[w2 * 64 + t];
        invn[t] = 1.f / fmaxf(sqrtf(s), 1e-12f);
    }
    __syncthreads();

    // ---- write normalized Tn bf16 (Pf + aliased scratch dead)
#pragma unroll
    for (int mi = 0; mi < 4; ++mi)
#pragma unroll
        for (int r = 0; r < 4; ++r) {
            int row = mi * 16 + quad * 4 + r;
            if (row < 51) {
                float iv = invn[row];
#pragma unroll
                for (int nj = 0; nj < 4; ++nj)
                    TnBuf[row * 520 + (wu * 4 + nj) * 16 + l15] = f2bf(acc[mi][nj][r] * iv);
            }
        }
    __syncthreads();

    // ---- phase 2: U = Qbb @ Tn^T; A-stream prefetch depth 4 (named regs, static indices)
    const u16* Qbf = Qbbf + (size_t)i * 6 * 16 * 512;
    f32x4 ua[3];
#pragma unroll
    for (int e = 0; e < 3; ++e) ua[e] = (f32x4){0.f, 0.f, 0.f, 0.f};

    if (wu < 6) {
        const u16* Ar = Qbf + (size_t)wu * 16 * 512 + lane * 8;
        bf16x8 Aa = ld_bf8(Ar + 0 * 512);
        bf16x8 Ab = ld_bf8(Ar + 1 * 512);
        bf16x8 Ac = ld_bf8(Ar + 2 * 512);
        bf16x8 Ad = ld_bf8(Ar + 3 * 512);
#pragma unroll
        for (int g = 0; g < 4; ++g) {
            bf16x8 Na, Nb, Nc, Nd;
            if (g < 3) {
                Na = ld_bf8(Ar + (g * 4 + 4) * 512);
                Nb = ld_bf8(Ar + (g * 4 + 5) * 512);
                Nc = ld_bf8(Ar + (g * 4 + 6) * 512);
                Nd = ld_bf8(Ar + (g * 4 + 7) * 512);
            }
#pragma unroll
            for (int e = 0; e < 3; ++e) {
                const u16* Tb = TnBuf + (e * 16 + l15) * 520 + quad * 8;
                ua[e] = __builtin_amdgcn_mfma_f32_16x16x32_bf16(Aa, ld_bf8(Tb + (g * 4 + 0) * 32), ua[e], 0, 0, 0);
                ua[e] = __builtin_amdgcn_mfma_f32_16x16x32_bf16(Ab, ld_bf8(Tb + (g * 4 + 1) * 32), ua[e], 0, 0, 0);
                ua[e] = __builtin_amdgcn_mfma_f32_16x16x32_bf16(Ac, ld_bf8(Tb + (g * 4 + 2) * 32), ua[e], 0, 0, 0);
                ua[e] = __builtin_amdgcn_mfma_f32_16x16x32_bf16(Ad, ld_bf8(Tb + (g * 4 + 3) * 32), ua[e], 0, 0, 0);
            }
            Aa = Na; Ab = Nb; Ac = Nc; Ad = Nd;
        }
    } else {
        int w2 = wu - 6;
        int rowB = 48 + l15; if (rowB > 50) rowB = 50;
        const u16* Ar0 = Qbf + (size_t)(3 * w2 + 0) * 16 * 512 + lane * 8;
        const u16* Ar1 = Qbf + (size_t)(3 * w2 + 1) * 16 * 512 + lane * 8;
        const u16* Ar2 = Qbf + (size_t)(3 * w2 + 2) * 16 * 512 + lane * 8;
        bf16x8 Af0 = ld_bf8(Ar0);
        bf16x8 Af1 = ld_bf8(Ar1);
        bf16x8 Af2 = ld_bf8(Ar2);
        for (int ks = 0; ks < 16; ++ks) {
            bf16x8 An0, An1, An2;
            if (ks < 15) {
                An0 = ld_bf8(Ar0 + (ks + 1) * 512);
                An1 = ld_bf8(Ar1 + (ks + 1) * 512);
                An2 = ld_bf8(Ar2 + (ks + 1) * 512);
            }
            bf16x8 Bf = ld_bf8(TnBuf + rowB * 520 + ks * 32 + quad * 8);
            ua[0] = __builtin_amdgcn_mfma_f32_16x16x32_bf16(Af0, Bf, ua[0], 0, 0, 0);
            ua[1] = __builtin_amdgcn_mfma_f32_16x16x32_bf16(Af1, Bf, ua[1], 0, 0, 0);
            ua[2] = __builtin_amdgcn_mfma_f32_16x16x32_bf16(Af2, Bf, ua[2], 0, 0, 0);
            Af0 = An0; Af1 = An1; Af2 = An2;
        }
    }
    __syncthreads();   // Tn reads done before U overwrites

    // ---- write U (96 x 51)
    if (wu < 6) {
#pragma unroll
        for (int e = 0; e < 3; ++e) {
            int l = e * 16 + l15;
            int q0 = wu * 16 + quad * 4;
#pragma unroll
            for (int r = 0; r < 4; ++r) ULDS[(q0 + r) * 52 + l] = ua[e][r];
        }
    } else {
        int l = 48 + l15;
        if (l < 51) {
            int w2 = wu - 6;
#pragma unroll
            for (int e = 0; e < 3; ++e) {
                int q0 = (3 * w2 + e) * 16 + quad * 4;
#pragma unroll
                for (int r = 0; r < 4; ++r) ULDS[(q0 + r) * 52 + l] = ua[e][r];
            }
        }
    }
    __syncthreads();

    // ---- softmax: compute exp(v-m)/Z and write normalized probs BACK into ULDS
    float invT = 1.f / temp_p[0];
    if (t < 408) {
        int l = t >> 3, sub = t & 7;
        float vbuf[4]; float mm = -1e30f;
#pragma unroll
        for (int q = 0; q < 4; ++q) {
            float v = ULDS[(32 + sub + 8 * q) * 52 + l] * invT;
            vbuf[q] = v;
            mm = fmaxf(mm, v);
        }
#pragma unroll
        for (int o = 1; o < 8; o <<= 1) mm = fmaxf(mm, __shfl_xor(mm, o, 8));
        float e[4]; float z = 0.f;
#pragma unroll
        for (int q = 0; q < 4; ++q) { e[q] = expf(vbuf[q] - mm); z += e[q]; }
#pragma unroll
        for (int o = 1; o < 8; o <<= 1) z += __shfl_xor(z, o, 8);
        float iz = 1.f / z;
#pragma unroll
        for (int q = 0; q < 4; ++q) ULDS[(32 + sub + 8 * q) * 52 + l] = e[q] * iz;
    }
    if (t < 256) {
        int u = t >> 3, sub = t & 7;
        float vbuf[7]; int cnt = 0; float mm = -1e30f;
        for (int l = sub; l < 51; l += 8) {
            float v = ULDS[(64 + u) * 52 + l] * invT;
            vbuf[cnt++] = v;
            mm = fmaxf(mm, v);
        }
#pragma unroll
        for (int o = 1; o < 8; o <<= 1) mm = fmaxf(mm, __shfl_xor(mm, o, 8));
        float e[7]; float z = 0.f;
        for (int q = 0; q < cnt; ++q) { e[q] = expf(vbuf[q] - mm); z += e[q]; }
#pragma unroll
        for (int o = 1; o < 8; o <<= 1) z += __shfl_xor(z, o, 8);
        float iz = 1.f / z;
        { int q = 0;
          for (int l = sub; l < 51; l += 8) { ULDS[(64 + u) * 52 + l] = e[q] * iz; ++q; } }
    }
    __syncthreads();

    // ---- final reduction (probs precomputed); incremental (u,l) stepping
    float part = 0.f;
    {
        int u = t / 51, l = t - (t / 51) * 51;
        while (u < LT) {
            float u0 = ULDS[u * 52 + l];
            float c2 = (u0 > 0.f) ? u0 : 0.1f * u0;
            float av = ULDS[(32 + u) * 52 + l];
            float bv = ULDS[(64 + u) * 52 + l];
            part += c2 * (av * (1.f / 51.f) + bv * (1.f / 32.f));
            u += 10; l += 2;                           // += 512 = 10*51 + 2
            if (l >= 51) { l -= 51; ++u; }
        }
    }
    for (int o = 32; o > 0; o >>= 1) part += __shfl_down(part, o);
    if (lane == 0) redw[wu] = part;
    __syncthreads();
    if (t == 0) {
        float s = 0.f;
#pragma unroll
        for (int w2 = 0; w2 < 8; ++w2) s += redw[w2];
        out[b * NCAP + i] = s;
    }
}

extern "C" void kernel_launch(void* const* d_in, const int* in_sizes, int n_in,
                              void* d_out, int out_size, void* d_ws, size_t ws_size,
                              hipStream_t stream) {
    const float* img        = (const float*)d_in[0];
    const float* cap        = (const float*)d_in[1];
    const float* gamw       = (const float*)d_in[3];
    const float* betw       = (const float*)d_in[4];
    const float* w1         = (const float*)d_in[5];
    const float* b1         = (const float*)d_in[6];
    const float* w2         = (const float*)d_in[7];
    const float* b2         = (const float*)d_in[8];
    const float* aggr_scale = (const float*)d_in[9];
    const float* wi2t       = (const float*)d_in[10];
    const float* bi2t       = (const float*)d_in[11];
    const float* wt2i       = (const float*)d_in[12];
    const float* bt2i       = (const float*)d_in[13];
    const float* temp       = (const float*)d_in[14];
    float* out = (float*)d_out;

    float* ws      = (float*)d_ws;
    float* attn_x  = ws + OFF_ATTNX;
    u16*   WsM16   = (u16*)(ws + OFF_WSMAT);
    u16*   wT      = (u16*)(ws + OFF_WT);
    float* gloT    = ws + OFF_GLOT;
    float* attn_yT = ws + OFF_ATTNYT;
    u16*   imgTf   = (u16*)(ws + OFF_IMGT);
    u16*   Qbbf    = (u16*)(ws + OFF_QBB);
    u16*   Qcap    = (u16*)(ws + OFF_QCAP);
    u16*   w1Tf    = (u16*)(ws + OFF_W1TF);
    u16*   w2Tf    = (u16*)(ws + OFF_W2TF);

    k_pre<<<dim3(648), dim3(256), 0, stream>>>(cap, wi2t, wt2i, w1, w2,
                                               gloT, Qbbf, Qcap, wT, w1Tf, w2Tf);
    k_mid<<<dim3(3200), dim3(512), 0, stream>>>(img, wT, bi2t, bt2i, Qcap, Qbbf,
                                                w1Tf, w2Tf, gamw, betw, b1, b2, aggr_scale,
                                                gloT, attn_x, WsM16, attn_yT, imgTf);
    k_main<<<dim3(NCAP, B), dim3(512), 0, stream>>>(attn_x, attn_yT, WsM16, imgTf, Qbbf, temp, out);
}